// Round 8
// baseline (2649.604 us; speedup 1.0000x reference)
//
#include <hip/hip_runtime.h>
#include <cstdint>
#include <cstddef>

// ============================================================================
// ConditionalRBM sampler — bit-exact resimulation of the JAX reference.
//
// Round-8 post-mortem of R7: chunked double-buffering self-defeated — the
// next-chunk staging loads are oldest in the in-order VMEM queue, so the
// ds_write's waitcnt drained the chunk's entire w-load stream; 4 full
// pipeline restarts per k-loop (VALUBusy 28%, 45us).
// Round-8: same 32x64 block / 2x4 thread tile, but the WHOLE 256-k state
// slice [256k][32r] = 32 KiB is staged ONCE (single barrier). The 256-k
// loop is then pure {1 ds_read_b64 (4 addrs, broadcast, conflict-free) +
// 1 global float4 w-load (256B/wave, L2-hot) + 8 fma}, unroll 8 — no
// barriers, no drains. Grid 1024 -> 4 blocks/CU x 32KiB = 128KiB LDS,
// 16 waves/CU. Per-CU model: VALU ~9.5us, LDS ~4096 ds_b64 ~8us (overlap).
// Accumulation order per output unchanged: single ascending-k fma chain.
//
// ASSUMPTION STACK (verified bit-exact in earlier rounds):
//  A1: jax_threefry_partitionable = True:
//      split(key,n)[i] = TF(key,(0,i)); bits32[j] = TF0(key,(0,j)) ^ TF1(key,(0,j))
//  A2: logistic(x) = 1/(1+exp(-x)), IEEE fdiv
//  A3: exp = XLA-CPU vectorized Cephes/Eigen pexp
//  A4: dot = ascending-k single-accumulator fma chain (exact 0/1 products)
//  A5: x = (dot + udot) + bias association
//  Output dtype: int32 0/1 (harness reads d_out as int32).
// ============================================================================

#pragma clang fp contract(off)

#define BATCH 8192
#define NU 64
#define NF 256   // num_v == num_h == 256
#define RB 32    // rows per block in k_phase
#define CBL 64   // cols per block in k_phase
#define RTI 16   // rows per block in k_init / k_udot
#define THERM 24
#define NSAMP 8

// ---------------- Threefry-2x32 (JAX rotation/injection schedule) ----------
__host__ __device__ __forceinline__ void tf2x32(uint32_t k0, uint32_t k1,
                                                uint32_t x0, uint32_t x1,
                                                uint32_t* o0, uint32_t* o1) {
  uint32_t ks2 = k0 ^ k1 ^ 0x1BD11BDAu;
  x0 += k0; x1 += k1;
#define TFR(r) { x0 += x1; x1 = (x1 << (r)) | (x1 >> (32 - (r))); x1 ^= x0; }
  TFR(13) TFR(15) TFR(26) TFR(6)
  x0 += k1;  x1 += ks2 + 1u;
  TFR(17) TFR(29) TFR(16) TFR(24)
  x0 += ks2; x1 += k0 + 2u;
  TFR(13) TFR(15) TFR(26) TFR(6)
  x0 += k0;  x1 += k1 + 3u;
  TFR(17) TFR(29) TFR(16) TFR(24)
  x0 += k1;  x1 += ks2 + 4u;
  TFR(13) TFR(15) TFR(26) TFR(6)
  x0 += ks2; x1 += k0 + 5u;
#undef TFR
  *o0 = x0; *o1 = x1;
}

// ---------------- XLA-CPU expf (Cephes/Eigen polynomial) -------------------
__device__ __forceinline__ float xla_expf(float x) {
  float xc = fminf(x, 88.3762626647950f);
  xc = fmaxf(xc, -88.3762626647949f);
  float fx = floorf(__builtin_fmaf(xc, 1.44269504088896341f, 0.5f));
  float tmp = 0.693359375f * fx;          // separate rounding (contract off)
  float z = -2.12194440e-4f * fx;
  float r = xc - tmp;
  r = r - z;
  z = r * r;
  float y = __builtin_fmaf(r, 1.9875691500e-4f, 1.3981999507e-3f);
  y = __builtin_fmaf(y, r, 8.3334519073e-3f);
  y = __builtin_fmaf(y, r, 4.1665795894e-2f);
  y = __builtin_fmaf(y, r, 1.6666665459e-1f);
  y = __builtin_fmaf(y, r, 5.0000001201e-1f);
  y = __builtin_fmaf(y, z, r);
  y = y + 1.0f;
  int n = (int)fx;
  float p2 = __int_as_float((n + 127) << 23);
  float res = y * p2;
  return fmaxf(res, x);                   // Eigen pexp: pmax(res, original x)
}

__device__ __forceinline__ float sigmoid_ref(float x) {
  float e = xla_expf(-x);                 // negate exact
  return 1.0f / (1.0f + e);               // IEEE fdiv (no fast-math)
}

// bern: partitionable threefry bits -> uniform [0,1) -> (u < p)
__device__ __forceinline__ float bern_sample(uint32_t key0, uint32_t key1,
                                             uint32_t idx, float p) {
  uint32_t b0, b1;
  tf2x32(key0, key1, 0u, idx, &b0, &b1);  // counter = (hi=0, lo=flat_idx)
  uint32_t bits = b0 ^ b1;                // 32-bit path XORs both words
  float u = __uint_as_float((bits >> 9) | 0x3f800000u) - 1.0f;
  return (u < p) ? 1.0f : 0.0f;
}

// ---------------- kernels ---------------------------------------------------
__global__ void k_transpose(const float* __restrict__ Whv,
                            float* __restrict__ WhvT) {
  int j = threadIdx.x;  // hidden
  int k = blockIdx.x;   // visible
  WhvT[k * NF + j] = Whv[j * NF + k];
}

// out[row][j] = sum_k u[row][k] * W[j][k], ascending k (exact products).
// W row j lives in registers; u-chunk (RTI rows x 64) broadcast from LDS.
__global__ __launch_bounds__(256, 2) void k_udot(const float* __restrict__ U,
                                                 const float* __restrict__ W,
                                                 float* __restrict__ out) {
  __shared__ __align__(16) float Ulds[NU * RTI];  // [k][i], 4 KiB
  const int j = threadIdx.x;
  const int i0 = blockIdx.x * RTI;
  const int si = j & 15;          // row within tile
  const int sg = j >> 4;          // 4-col group (16 groups cover 64 cols)
  {
    float4 u4 = *(const float4*)(U + (size_t)(i0 + si) * NU + sg * 4);
    Ulds[(sg * 4 + 0) * RTI + si] = u4.x;
    Ulds[(sg * 4 + 1) * RTI + si] = u4.y;
    Ulds[(sg * 4 + 2) * RTI + si] = u4.z;
    Ulds[(sg * 4 + 3) * RTI + si] = u4.w;
  }
  float wreg[NU];
  const float4* wr4 = (const float4*)(W + (size_t)j * NU);
#pragma unroll
  for (int r = 0; r < NU / 4; ++r) {
    float4 t = wr4[r];
    wreg[4 * r + 0] = t.x; wreg[4 * r + 1] = t.y;
    wreg[4 * r + 2] = t.z; wreg[4 * r + 3] = t.w;
  }
  __syncthreads();
  float acc[RTI];
#pragma unroll
  for (int i = 0; i < RTI; ++i) acc[i] = 0.0f;
#pragma unroll
  for (int kk = 0; kk < NU; ++kk) {
    const float w = wreg[kk];
    const float4 s0 = *(const float4*)(&Ulds[kk * RTI + 0]);
    const float4 s1 = *(const float4*)(&Ulds[kk * RTI + 4]);
    const float4 s2 = *(const float4*)(&Ulds[kk * RTI + 8]);
    const float4 s3 = *(const float4*)(&Ulds[kk * RTI + 12]);
    acc[0]  = __builtin_fmaf(s0.x, w, acc[0]);
    acc[1]  = __builtin_fmaf(s0.y, w, acc[1]);
    acc[2]  = __builtin_fmaf(s0.z, w, acc[2]);
    acc[3]  = __builtin_fmaf(s0.w, w, acc[3]);
    acc[4]  = __builtin_fmaf(s1.x, w, acc[4]);
    acc[5]  = __builtin_fmaf(s1.y, w, acc[5]);
    acc[6]  = __builtin_fmaf(s1.z, w, acc[6]);
    acc[7]  = __builtin_fmaf(s1.w, w, acc[7]);
    acc[8]  = __builtin_fmaf(s2.x, w, acc[8]);
    acc[9]  = __builtin_fmaf(s2.y, w, acc[9]);
    acc[10] = __builtin_fmaf(s2.z, w, acc[10]);
    acc[11] = __builtin_fmaf(s2.w, w, acc[11]);
    acc[12] = __builtin_fmaf(s3.x, w, acc[12]);
    acc[13] = __builtin_fmaf(s3.y, w, acc[13]);
    acc[14] = __builtin_fmaf(s3.z, w, acc[14]);
    acc[15] = __builtin_fmaf(s3.w, w, acc[15]);
  }
#pragma unroll
  for (int i = 0; i < RTI; ++i)
    out[(size_t)(i0 + i) * NF + j] = acc[i];   // row-major C (coalesced)
}

// v0 = bern(ks[0], sigmoid(uv + bv)); writes transposed state Vt[j][row]
__global__ __launch_bounds__(256) void k_init(const float* __restrict__ uv,
                                              const float* __restrict__ bv,
                                              float* __restrict__ Vt,
                                              uint32_t key0, uint32_t key1) {
  int j = threadIdx.x;
  int i0 = blockIdx.x * RTI;
  float b = bv[j];
  float vals[RTI];
#pragma unroll
  for (int i = 0; i < RTI; ++i) {
    int row = i0 + i;
    uint32_t idx = (uint32_t)(row * NF + j);
    float x = uv[idx] + b;                // (dot) + bias : single add
    float p = sigmoid_ref(x);
    vals[i] = bern_sample(key0, key1, idx, p);
  }
  float4* dst = (float4*)(Vt + (size_t)j * BATCH + i0);
#pragma unroll
  for (int q = 0; q < RTI / 4; ++q)
    dst[q] = make_float4(vals[4 * q], vals[4 * q + 1], vals[4 * q + 2], vals[4 * q + 3]);
}

// One Gibbs half-step: O = bern(key, sigmoid((St^T @ W) + C + bias))
// St: prev state transposed [256 k][8192 i]; W: [256 k][256 j] k-major;
// C: u-dot row-major [8192][256]; Ot: next state transposed; smp: int32 out.
// Block = 32 rows x 64 cols, thread tile 2x4. FULL-k state slice
// [256k][32r] = 32 KiB staged once (1 barrier); then barrier-free 256-k
// loop: 1 ds_read_b64 (4 distinct addrs, 16-lane broadcast, conflict-free)
// + 1 global float4 w-load (256 B/wave, L2-hot) + 8 fma, unroll 8.
// Grid 1024 -> 4 blocks/CU (128 KiB LDS) -> 16 waves/CU.
__global__ __launch_bounds__(256, 4) void k_phase(const float* __restrict__ St,
                                                  const float* __restrict__ W,
                                                  const float* __restrict__ C,
                                                  const float* __restrict__ bias,
                                                  float* __restrict__ Ot,
                                                  int* __restrict__ smp,
                                                  uint32_t key0, uint32_t key1) {
  __shared__ __align__(16) float Slds[NF * RB];   // [k][row], 32 KiB
  const int t  = threadIdx.x;
  const int i0 = (blockIdx.x >> 2) * RB;   // 256 row-blocks
  const int c0 = (blockIdx.x & 3) * CBL;   // 4 col-blocks
  const int rg = t >> 4;                   // 16 row-groups x 2 rows
  const int cg = t & 15;                   // 16 col-groups x 4 cols
  const int jc = c0 + cg * 4;              // this thread's first col

  // stage the whole-k state slice: 2048 float4, 8 per thread.
  // f = q*256+t -> k = f>>3 (8 float4 per 128B k-row), r4 = f&7: coalesced.
  {
    const float* stbase = St + i0;
    float4* sl4 = (float4*)Slds;
#pragma unroll
    for (int q = 0; q < 8; ++q) {
      const int f  = q * 256 + t;
      const int k  = f >> 3;
      const int r4 = f & 7;
      sl4[f] = *(const float4*)(stbase + (size_t)k * BATCH + r4 * 4);
    }
  }
  __syncthreads();

  float acc[8];                       // acc[ri*4+ci], ri in {0,1}
#pragma unroll
  for (int q = 0; q < 8; ++q) acc[q] = 0.0f;

  const float* wp = W + jc;           // this thread's 4 cols, stride NF per k
  const float* sl = Slds + rg * 2;    // this thread's 2 rows in the slice

#pragma unroll 8
  for (int k = 0; k < NF; ++k) {
    const float4 w = *(const float4*)(wp + (size_t)k * NF);  // 256B/wave, L2-hot
    const float2 s = *(const float2*)(sl + k * RB);          // broadcast, no conflict
    acc[0] = __builtin_fmaf(s.x, w.x, acc[0]);   // exact product (0/1)
    acc[1] = __builtin_fmaf(s.x, w.y, acc[1]);
    acc[2] = __builtin_fmaf(s.x, w.z, acc[2]);
    acc[3] = __builtin_fmaf(s.x, w.w, acc[3]);
    acc[4] = __builtin_fmaf(s.y, w.x, acc[4]);
    acc[5] = __builtin_fmaf(s.y, w.y, acc[5]);
    acc[6] = __builtin_fmaf(s.y, w.z, acc[6]);
    acc[7] = __builtin_fmaf(s.y, w.w, acc[7]);
  }

  // epilogue: x = (dot + udot) + bias ; p = sigmoid ; bern ; store
  const float4 b4 = *(const float4*)(bias + jc);
  float vals[8];
#pragma unroll
  for (int ri = 0; ri < 2; ++ri) {
    const int row = i0 + rg * 2 + ri;
    const float4 c4 = *(const float4*)(C + (size_t)row * NF + jc);
    const uint32_t idx0 = (uint32_t)(row * NF + jc);
    vals[ri * 4 + 0] = bern_sample(key0, key1, idx0 + 0,
        sigmoid_ref((acc[ri * 4 + 0] + c4.x) + b4.x));
    vals[ri * 4 + 1] = bern_sample(key0, key1, idx0 + 1,
        sigmoid_ref((acc[ri * 4 + 1] + c4.y) + b4.y));
    vals[ri * 4 + 2] = bern_sample(key0, key1, idx0 + 2,
        sigmoid_ref((acc[ri * 4 + 2] + c4.z) + b4.z));
    vals[ri * 4 + 3] = bern_sample(key0, key1, idx0 + 3,
        sigmoid_ref((acc[ri * 4 + 3] + c4.w) + b4.w));
  }

  // next-state store (transposed): per col, the thread's 2 contiguous rows
#pragma unroll
  for (int ci = 0; ci < 4; ++ci) {
    *(float2*)(Ot + (size_t)(jc + ci) * BATCH + i0 + rg * 2) =
        make_float2(vals[0 + ci], vals[4 + ci]);
  }
  if (smp) {                          // row-major int32 sample output
#pragma unroll
    for (int ri = 0; ri < 2; ++ri) {
      const int row = i0 + rg * 2 + ri;
      int4 o;
      o.x = (vals[ri * 4 + 0] != 0.0f) ? 1 : 0;
      o.y = (vals[ri * 4 + 1] != 0.0f) ? 1 : 0;
      o.z = (vals[ri * 4 + 2] != 0.0f) ? 1 : 0;
      o.w = (vals[ri * 4 + 3] != 0.0f) ? 1 : 0;
      *(int4*)(smp + (size_t)row * NF + jc) = o;
    }
  }
}

// ---------------- launch ----------------------------------------------------
extern "C" void kernel_launch(void* const* d_in, const int* in_sizes, int n_in,
                              void* d_out, int out_size, void* d_ws, size_t ws_size,
                              hipStream_t stream) {
  const float* u_state = (const float*)d_in[0];  // [8192][64] 0/1 floats
  const float* Wvu     = (const float*)d_in[1];  // [256][64]
  const float* Whu     = (const float*)d_in[2];  // [256][64]
  const float* Whv     = (const float*)d_in[3];  // [256][256]
  const float* bv      = (const float*)d_in[4];  // [256]
  const float* bh      = (const float*)d_in[5];  // [256]
  int* out = (int*)d_out;                        // [8][8192][256] as int32 0/1

  // workspace layout (floats); total 8,454,144 f32 = 33.8 MB
  float* ws   = (float*)d_ws;
  float* WhvT = ws;                        // 65536
  float* uh   = WhvT + NF * NF;            // row-major [8192][256]
  float* uv   = uh + (size_t)BATCH * NF;
  float* Vt   = uv + (size_t)BATCH * NF;   // state, transposed [256][8192]
  float* Ht   = Vt + (size_t)BATCH * NF;

  // ---- host-side key schedule (pure CPU, deterministic) ----
  uint32_t s0[THERM + NSAMP + 1], s1[THERM + NSAMP + 1];
  for (uint32_t i = 0; i < THERM + NSAMP + 1; ++i)
    tf2x32(0u, 1u, 0u, i, &s0[i], &s1[i]);

  k_transpose<<<NF, NF, 0, stream>>>(Whv, WhvT);
  k_udot<<<BATCH / RTI, NF, 0, stream>>>(u_state, Whu, uh);   // u @ Whu.T
  k_udot<<<BATCH / RTI, NF, 0, stream>>>(u_state, Wvu, uv);   // u @ Wvu.T
  k_init<<<BATCH / RTI, NF, 0, stream>>>(uv, bv, Vt, s0[0], s1[0]);

  const int phase_blocks = (BATCH / RB) * (NF / CBL);   // 256 * 4 = 1024
  for (int t = 0; t < THERM + NSAMP; ++t) {
    uint32_t kh0, kh1, kv0, kv1;
    tf2x32(s0[1 + t], s1[1 + t], 0u, 0u, &kh0, &kh1);
    tf2x32(s0[1 + t], s1[1 + t], 0u, 1u, &kv0, &kv1);
    int* smp = (t >= THERM) ? out + (size_t)(t - THERM) * BATCH * NF : (int*)nullptr;
    // h = bern(k1, sigmoid(v @ Whv.T + uh + bh))
    k_phase<<<phase_blocks, NF, 0, stream>>>(Vt, WhvT, uh, bh, Ht, (int*)nullptr, kh0, kh1);
    // v = bern(k2, sigmoid(h @ Whv + uv + bv)) ; emit sample when t>=THERM
    k_phase<<<phase_blocks, NF, 0, stream>>>(Ht, Whv, uv, bv, Vt, smp, kv0, kv1);
  }
  (void)in_sizes; (void)n_in; (void)out_size; (void)ws_size;
}

// Round 9
// 2558.785 us; speedup vs baseline: 1.0355x; 1.0355x over previous
//
#include <hip/hip_runtime.h>
#include <cstdint>
#include <cstddef>

// ============================================================================
// ConditionalRBM sampler — bit-exact resimulation of the JAX reference.
//
// Round-9 post-mortem of R8: k-loop ran at one L2 round-trip PER ITERATION.
// VGPR=44 proves the compiler issued each w-load right before its use
// (no software pipelining despite #pragma unroll 8) -> 430 cy wall per
// 16 cy of fma, VALUBusy 26%.
// Round-9: R8 skeleton (full-k state slice in LDS once, barrier-free loop)
// + EXPLICIT 2-stage software pipeline with named A/B register sets
// (groups of 4 k; group g+1's 4 w-loads + 4 s-reads issue before group g's
// 32 fma) -> ~250-300 cy slack per load at 4 waves/SIMD >= L2 latency.
// Also: co-resident blocks share the same W col-slice (c0 = blockIdx>>8)
// so followers ride L1/L2-hot W lines.
// Accumulation order per output unchanged: ascending-k single-acc fma chain.
//
// ASSUMPTION STACK (verified bit-exact in earlier rounds):
//  A1: jax_threefry_partitionable = True:
//      split(key,n)[i] = TF(key,(0,i)); bits32[j] = TF0(key,(0,j)) ^ TF1(key,(0,j))
//  A2: logistic(x) = 1/(1+exp(-x)), IEEE fdiv
//  A3: exp = XLA-CPU vectorized Cephes/Eigen pexp
//  A4: dot = ascending-k single-accumulator fma chain (exact 0/1 products)
//  A5: x = (dot + udot) + bias association
//  Output dtype: int32 0/1 (harness reads d_out as int32).
// ============================================================================

#pragma clang fp contract(off)

#define BATCH 8192
#define NU 64
#define NF 256   // num_v == num_h == 256
#define RB 32    // rows per block in k_phase
#define CBL 64   // cols per block in k_phase
#define RTI 16   // rows per block in k_init / k_udot
#define THERM 24
#define NSAMP 8

// ---------------- Threefry-2x32 (JAX rotation/injection schedule) ----------
__host__ __device__ __forceinline__ void tf2x32(uint32_t k0, uint32_t k1,
                                                uint32_t x0, uint32_t x1,
                                                uint32_t* o0, uint32_t* o1) {
  uint32_t ks2 = k0 ^ k1 ^ 0x1BD11BDAu;
  x0 += k0; x1 += k1;
#define TFR(r) { x0 += x1; x1 = (x1 << (r)) | (x1 >> (32 - (r))); x1 ^= x0; }
  TFR(13) TFR(15) TFR(26) TFR(6)
  x0 += k1;  x1 += ks2 + 1u;
  TFR(17) TFR(29) TFR(16) TFR(24)
  x0 += ks2; x1 += k0 + 2u;
  TFR(13) TFR(15) TFR(26) TFR(6)
  x0 += k0;  x1 += k1 + 3u;
  TFR(17) TFR(29) TFR(16) TFR(24)
  x0 += k1;  x1 += ks2 + 4u;
  TFR(13) TFR(15) TFR(26) TFR(6)
  x0 += ks2; x1 += k0 + 5u;
#undef TFR
  *o0 = x0; *o1 = x1;
}

// ---------------- XLA-CPU expf (Cephes/Eigen polynomial) -------------------
__device__ __forceinline__ float xla_expf(float x) {
  float xc = fminf(x, 88.3762626647950f);
  xc = fmaxf(xc, -88.3762626647949f);
  float fx = floorf(__builtin_fmaf(xc, 1.44269504088896341f, 0.5f));
  float tmp = 0.693359375f * fx;          // separate rounding (contract off)
  float z = -2.12194440e-4f * fx;
  float r = xc - tmp;
  r = r - z;
  z = r * r;
  float y = __builtin_fmaf(r, 1.9875691500e-4f, 1.3981999507e-3f);
  y = __builtin_fmaf(y, r, 8.3334519073e-3f);
  y = __builtin_fmaf(y, r, 4.1665795894e-2f);
  y = __builtin_fmaf(y, r, 1.6666665459e-1f);
  y = __builtin_fmaf(y, r, 5.0000001201e-1f);
  y = __builtin_fmaf(y, z, r);
  y = y + 1.0f;
  int n = (int)fx;
  float p2 = __int_as_float((n + 127) << 23);
  float res = y * p2;
  return fmaxf(res, x);                   // Eigen pexp: pmax(res, original x)
}

__device__ __forceinline__ float sigmoid_ref(float x) {
  float e = xla_expf(-x);                 // negate exact
  return 1.0f / (1.0f + e);               // IEEE fdiv (no fast-math)
}

// bern: partitionable threefry bits -> uniform [0,1) -> (u < p)
__device__ __forceinline__ float bern_sample(uint32_t key0, uint32_t key1,
                                             uint32_t idx, float p) {
  uint32_t b0, b1;
  tf2x32(key0, key1, 0u, idx, &b0, &b1);  // counter = (hi=0, lo=flat_idx)
  uint32_t bits = b0 ^ b1;                // 32-bit path XORs both words
  float u = __uint_as_float((bits >> 9) | 0x3f800000u) - 1.0f;
  return (u < p) ? 1.0f : 0.0f;
}

// ---------------- kernels ---------------------------------------------------
__global__ void k_transpose(const float* __restrict__ Whv,
                            float* __restrict__ WhvT) {
  int j = threadIdx.x;  // hidden
  int k = blockIdx.x;   // visible
  WhvT[k * NF + j] = Whv[j * NF + k];
}

// out[row][j] = sum_k u[row][k] * W[j][k], ascending k (exact products).
// W row j lives in registers; u-chunk (RTI rows x 64) broadcast from LDS.
__global__ __launch_bounds__(256, 2) void k_udot(const float* __restrict__ U,
                                                 const float* __restrict__ W,
                                                 float* __restrict__ out) {
  __shared__ __align__(16) float Ulds[NU * RTI];  // [k][i], 4 KiB
  const int j = threadIdx.x;
  const int i0 = blockIdx.x * RTI;
  const int si = j & 15;          // row within tile
  const int sg = j >> 4;          // 4-col group (16 groups cover 64 cols)
  {
    float4 u4 = *(const float4*)(U + (size_t)(i0 + si) * NU + sg * 4);
    Ulds[(sg * 4 + 0) * RTI + si] = u4.x;
    Ulds[(sg * 4 + 1) * RTI + si] = u4.y;
    Ulds[(sg * 4 + 2) * RTI + si] = u4.z;
    Ulds[(sg * 4 + 3) * RTI + si] = u4.w;
  }
  float wreg[NU];
  const float4* wr4 = (const float4*)(W + (size_t)j * NU);
#pragma unroll
  for (int r = 0; r < NU / 4; ++r) {
    float4 t = wr4[r];
    wreg[4 * r + 0] = t.x; wreg[4 * r + 1] = t.y;
    wreg[4 * r + 2] = t.z; wreg[4 * r + 3] = t.w;
  }
  __syncthreads();
  float acc[RTI];
#pragma unroll
  for (int i = 0; i < RTI; ++i) acc[i] = 0.0f;
#pragma unroll
  for (int kk = 0; kk < NU; ++kk) {
    const float w = wreg[kk];
    const float4 s0 = *(const float4*)(&Ulds[kk * RTI + 0]);
    const float4 s1 = *(const float4*)(&Ulds[kk * RTI + 4]);
    const float4 s2 = *(const float4*)(&Ulds[kk * RTI + 8]);
    const float4 s3 = *(const float4*)(&Ulds[kk * RTI + 12]);
    acc[0]  = __builtin_fmaf(s0.x, w, acc[0]);
    acc[1]  = __builtin_fmaf(s0.y, w, acc[1]);
    acc[2]  = __builtin_fmaf(s0.z, w, acc[2]);
    acc[3]  = __builtin_fmaf(s0.w, w, acc[3]);
    acc[4]  = __builtin_fmaf(s1.x, w, acc[4]);
    acc[5]  = __builtin_fmaf(s1.y, w, acc[5]);
    acc[6]  = __builtin_fmaf(s1.z, w, acc[6]);
    acc[7]  = __builtin_fmaf(s1.w, w, acc[7]);
    acc[8]  = __builtin_fmaf(s2.x, w, acc[8]);
    acc[9]  = __builtin_fmaf(s2.y, w, acc[9]);
    acc[10] = __builtin_fmaf(s2.z, w, acc[10]);
    acc[11] = __builtin_fmaf(s2.w, w, acc[11]);
    acc[12] = __builtin_fmaf(s3.x, w, acc[12]);
    acc[13] = __builtin_fmaf(s3.y, w, acc[13]);
    acc[14] = __builtin_fmaf(s3.z, w, acc[14]);
    acc[15] = __builtin_fmaf(s3.w, w, acc[15]);
  }
#pragma unroll
  for (int i = 0; i < RTI; ++i)
    out[(size_t)(i0 + i) * NF + j] = acc[i];   // row-major C (coalesced)
}

// v0 = bern(ks[0], sigmoid(uv + bv)); writes transposed state Vt[j][row]
__global__ __launch_bounds__(256) void k_init(const float* __restrict__ uv,
                                              const float* __restrict__ bv,
                                              float* __restrict__ Vt,
                                              uint32_t key0, uint32_t key1) {
  int j = threadIdx.x;
  int i0 = blockIdx.x * RTI;
  float b = bv[j];
  float vals[RTI];
#pragma unroll
  for (int i = 0; i < RTI; ++i) {
    int row = i0 + i;
    uint32_t idx = (uint32_t)(row * NF + j);
    float x = uv[idx] + b;                // (dot) + bias : single add
    float p = sigmoid_ref(x);
    vals[i] = bern_sample(key0, key1, idx, p);
  }
  float4* dst = (float4*)(Vt + (size_t)j * BATCH + i0);
#pragma unroll
  for (int q = 0; q < RTI / 4; ++q)
    dst[q] = make_float4(vals[4 * q], vals[4 * q + 1], vals[4 * q + 2], vals[4 * q + 3]);
}

// One Gibbs half-step: O = bern(key, sigmoid((St^T @ W) + C + bias))
// St: prev state transposed [256 k][8192 i]; W: [256 k][256 j] k-major;
// C: u-dot row-major [8192][256]; Ot: next state transposed; smp: int32 out.
// Block = 32 rows x 64 cols, thread tile 2x4. Full-k state slice
// [256k][32r] = 32 KiB staged once (1 barrier). k-loop = explicit 2-stage
// software pipeline (named A/B register groups of 4 k): group g+1's loads
// are in flight while group g's 32 fma execute. Grid 1024 -> 4 blocks/CU;
// c0 = blockIdx>>8 so co-resident blocks share the same 64KB W slice.
__global__ __launch_bounds__(256, 4) void k_phase(const float* __restrict__ St,
                                                  const float* __restrict__ W,
                                                  const float* __restrict__ C,
                                                  const float* __restrict__ bias,
                                                  float* __restrict__ Ot,
                                                  int* __restrict__ smp,
                                                  uint32_t key0, uint32_t key1) {
  __shared__ __align__(16) float Slds[NF * RB];   // [k][row], 32 KiB
  const int t  = threadIdx.x;
  const int i0 = (blockIdx.x & 255) * RB;  // 256 row-blocks (consecutive ids)
  const int c0 = (blockIdx.x >> 8) * CBL;  // 4 col-blocks (CU-mates share W)
  const int rg = t >> 4;                   // 16 row-groups x 2 rows
  const int cg = t & 15;                   // 16 col-groups x 4 cols
  const int jc = c0 + cg * 4;              // this thread's first col

  // stage the whole-k state slice: 2048 float4, 8 per thread.
  // f = q*256+t -> k = f>>3 (8 float4 per 128B k-row), r4 = f&7: coalesced.
  {
    const float* stbase = St + i0;
    float4* sl4 = (float4*)Slds;
#pragma unroll
    for (int q = 0; q < 8; ++q) {
      const int f  = q * 256 + t;
      const int k  = f >> 3;
      const int r4 = f & 7;
      sl4[f] = *(const float4*)(stbase + (size_t)k * BATCH + r4 * 4);
    }
  }
  __syncthreads();

  float acc[8];                       // acc[ri*4+ci], ri in {0,1}
#pragma unroll
  for (int q = 0; q < 8; ++q) acc[q] = 0.0f;

  const float* wp = W + jc;           // this thread's 4 cols, stride NF per k
  const float* sl = Slds + rg * 2;    // this thread's 2 rows in the slice

  // ---- explicit 2-stage software pipeline, groups of 4 k ----
  float4 wA[4], wB[4];
  float2 sA[4], sB[4];
#define LDW(dst, kb)                                                      \
  _Pragma("unroll") for (int q = 0; q < 4; ++q)                           \
    dst[q] = *(const float4*)(wp + (size_t)((kb) + q) * NF);
#define LDSR(dst, kb)                                                     \
  _Pragma("unroll") for (int q = 0; q < 4; ++q)                           \
    dst[q] = *(const float2*)(sl + ((kb) + q) * RB);
#define FMA4(wb, sb)                                                      \
  _Pragma("unroll") for (int q = 0; q < 4; ++q) {                         \
    acc[0] = __builtin_fmaf(sb[q].x, wb[q].x, acc[0]);                    \
    acc[1] = __builtin_fmaf(sb[q].x, wb[q].y, acc[1]);                    \
    acc[2] = __builtin_fmaf(sb[q].x, wb[q].z, acc[2]);                    \
    acc[3] = __builtin_fmaf(sb[q].x, wb[q].w, acc[3]);                    \
    acc[4] = __builtin_fmaf(sb[q].y, wb[q].x, acc[4]);                    \
    acc[5] = __builtin_fmaf(sb[q].y, wb[q].y, acc[5]);                    \
    acc[6] = __builtin_fmaf(sb[q].y, wb[q].z, acc[6]);                    \
    acc[7] = __builtin_fmaf(sb[q].y, wb[q].w, acc[7]);                    \
  }

  LDW(wA, 0); LDSR(sA, 0);
  for (int kb = 0; kb < NF; kb += 8) {
    LDW(wB, kb + 4); LDSR(sB, kb + 4);     // prefetch group g+1
    FMA4(wA, sA);                          // compute group g (k ascending)
    if (kb + 8 < NF) { LDW(wA, kb + 8); LDSR(sA, kb + 8); }  // prefetch g+2
    FMA4(wB, sB);                          // compute group g+1
  }
#undef LDW
#undef LDSR
#undef FMA4

  // epilogue: x = (dot + udot) + bias ; p = sigmoid ; bern ; store
  const float4 b4 = *(const float4*)(bias + jc);
  float vals[8];
#pragma unroll
  for (int ri = 0; ri < 2; ++ri) {
    const int row = i0 + rg * 2 + ri;
    const float4 c4 = *(const float4*)(C + (size_t)row * NF + jc);
    const uint32_t idx0 = (uint32_t)(row * NF + jc);
    vals[ri * 4 + 0] = bern_sample(key0, key1, idx0 + 0,
        sigmoid_ref((acc[ri * 4 + 0] + c4.x) + b4.x));
    vals[ri * 4 + 1] = bern_sample(key0, key1, idx0 + 1,
        sigmoid_ref((acc[ri * 4 + 1] + c4.y) + b4.y));
    vals[ri * 4 + 2] = bern_sample(key0, key1, idx0 + 2,
        sigmoid_ref((acc[ri * 4 + 2] + c4.z) + b4.z));
    vals[ri * 4 + 3] = bern_sample(key0, key1, idx0 + 3,
        sigmoid_ref((acc[ri * 4 + 3] + c4.w) + b4.w));
  }

  // next-state store (transposed): per col, the thread's 2 contiguous rows
#pragma unroll
  for (int ci = 0; ci < 4; ++ci) {
    *(float2*)(Ot + (size_t)(jc + ci) * BATCH + i0 + rg * 2) =
        make_float2(vals[0 + ci], vals[4 + ci]);
  }
  if (smp) {                          // row-major int32 sample output
#pragma unroll
    for (int ri = 0; ri < 2; ++ri) {
      const int row = i0 + rg * 2 + ri;
      int4 o;
      o.x = (vals[ri * 4 + 0] != 0.0f) ? 1 : 0;
      o.y = (vals[ri * 4 + 1] != 0.0f) ? 1 : 0;
      o.z = (vals[ri * 4 + 2] != 0.0f) ? 1 : 0;
      o.w = (vals[ri * 4 + 3] != 0.0f) ? 1 : 0;
      *(int4*)(smp + (size_t)row * NF + jc) = o;
    }
  }
}

// ---------------- launch ----------------------------------------------------
extern "C" void kernel_launch(void* const* d_in, const int* in_sizes, int n_in,
                              void* d_out, int out_size, void* d_ws, size_t ws_size,
                              hipStream_t stream) {
  const float* u_state = (const float*)d_in[0];  // [8192][64] 0/1 floats
  const float* Wvu     = (const float*)d_in[1];  // [256][64]
  const float* Whu     = (const float*)d_in[2];  // [256][64]
  const float* Whv     = (const float*)d_in[3];  // [256][256]
  const float* bv      = (const float*)d_in[4];  // [256]
  const float* bh      = (const float*)d_in[5];  // [256]
  int* out = (int*)d_out;                        // [8][8192][256] as int32 0/1

  // workspace layout (floats); total 8,454,144 f32 = 33.8 MB
  float* ws   = (float*)d_ws;
  float* WhvT = ws;                        // 65536
  float* uh   = WhvT + NF * NF;            // row-major [8192][256]
  float* uv   = uh + (size_t)BATCH * NF;
  float* Vt   = uv + (size_t)BATCH * NF;   // state, transposed [256][8192]
  float* Ht   = Vt + (size_t)BATCH * NF;

  // ---- host-side key schedule (pure CPU, deterministic) ----
  uint32_t s0[THERM + NSAMP + 1], s1[THERM + NSAMP + 1];
  for (uint32_t i = 0; i < THERM + NSAMP + 1; ++i)
    tf2x32(0u, 1u, 0u, i, &s0[i], &s1[i]);

  k_transpose<<<NF, NF, 0, stream>>>(Whv, WhvT);
  k_udot<<<BATCH / RTI, NF, 0, stream>>>(u_state, Whu, uh);   // u @ Whu.T
  k_udot<<<BATCH / RTI, NF, 0, stream>>>(u_state, Wvu, uv);   // u @ Wvu.T
  k_init<<<BATCH / RTI, NF, 0, stream>>>(uv, bv, Vt, s0[0], s1[0]);

  const int phase_blocks = (BATCH / RB) * (NF / CBL);   // 256 * 4 = 1024
  for (int t = 0; t < THERM + NSAMP; ++t) {
    uint32_t kh0, kh1, kv0, kv1;
    tf2x32(s0[1 + t], s1[1 + t], 0u, 0u, &kh0, &kh1);
    tf2x32(s0[1 + t], s1[1 + t], 0u, 1u, &kv0, &kv1);
    int* smp = (t >= THERM) ? out + (size_t)(t - THERM) * BATCH * NF : (int*)nullptr;
    // h = bern(k1, sigmoid(v @ Whv.T + uh + bh))
    k_phase<<<phase_blocks, NF, 0, stream>>>(Vt, WhvT, uh, bh, Ht, (int*)nullptr, kh0, kh1);
    // v = bern(k2, sigmoid(h @ Whv + uv + bv)) ; emit sample when t>=THERM
    k_phase<<<phase_blocks, NF, 0, stream>>>(Ht, Whv, uv, bv, Vt, smp, kv0, kv1);
  }
  (void)in_sizes; (void)n_in; (void)out_size; (void)ws_size;
}

// Round 10
// 2539.532 us; speedup vs baseline: 1.0433x; 1.0076x over previous
//
#include <hip/hip_runtime.h>
#include <cstdint>
#include <cstddef>

// ============================================================================
// ConditionalRBM sampler — bit-exact resimulation of the JAX reference.
//
// Round-10 post-mortem of R9: VGPR=44 < the 48 needed for the named A/B
// register sets -> the allocator never kept both sets live; the scheduler
// sank every prefetch back to just-before-use (legal: no dependence).
// Source-level pipelining has now been defeated twice by hipcc's
// pressure-minimizing scheduler. (c0-sharing worked: FETCH 20.8->9.3 MB,
// time unchanged -> pure latency.)
// Round-10: same skeleton + T19 sched_group_barrier to PIN the interleave:
// per phase {4 VMEM_READ(0x20), 4 DS_READ(0x100), 32 VALU(0x2)}; last
// iteration peeled so the loop body is branchless (a branch would split
// the scheduling region). Loads are then forced a full group ahead of
// their use -> counted vmcnt(4) waits instead of load-use serialization.
// Accumulation order per output unchanged: ascending-k single-acc fma chain.
//
// ASSUMPTION STACK (verified bit-exact in earlier rounds):
//  A1: jax_threefry_partitionable = True:
//      split(key,n)[i] = TF(key,(0,i)); bits32[j] = TF0(key,(0,j)) ^ TF1(key,(0,j))
//  A2: logistic(x) = 1/(1+exp(-x)), IEEE fdiv
//  A3: exp = XLA-CPU vectorized Cephes/Eigen pexp
//  A4: dot = ascending-k single-accumulator fma chain (exact 0/1 products)
//  A5: x = (dot + udot) + bias association
//  Output dtype: int32 0/1 (harness reads d_out as int32).
// ============================================================================

#pragma clang fp contract(off)

#define BATCH 8192
#define NU 64
#define NF 256   // num_v == num_h == 256
#define RB 32    // rows per block in k_phase
#define CBL 64   // cols per block in k_phase
#define RTI 16   // rows per block in k_init / k_udot
#define THERM 24
#define NSAMP 8

// ---------------- Threefry-2x32 (JAX rotation/injection schedule) ----------
__host__ __device__ __forceinline__ void tf2x32(uint32_t k0, uint32_t k1,
                                                uint32_t x0, uint32_t x1,
                                                uint32_t* o0, uint32_t* o1) {
  uint32_t ks2 = k0 ^ k1 ^ 0x1BD11BDAu;
  x0 += k0; x1 += k1;
#define TFR(r) { x0 += x1; x1 = (x1 << (r)) | (x1 >> (32 - (r))); x1 ^= x0; }
  TFR(13) TFR(15) TFR(26) TFR(6)
  x0 += k1;  x1 += ks2 + 1u;
  TFR(17) TFR(29) TFR(16) TFR(24)
  x0 += ks2; x1 += k0 + 2u;
  TFR(13) TFR(15) TFR(26) TFR(6)
  x0 += k0;  x1 += k1 + 3u;
  TFR(17) TFR(29) TFR(16) TFR(24)
  x0 += k1;  x1 += ks2 + 4u;
  TFR(13) TFR(15) TFR(26) TFR(6)
  x0 += ks2; x1 += k0 + 5u;
#undef TFR
  *o0 = x0; *o1 = x1;
}

// ---------------- XLA-CPU expf (Cephes/Eigen polynomial) -------------------
__device__ __forceinline__ float xla_expf(float x) {
  float xc = fminf(x, 88.3762626647950f);
  xc = fmaxf(xc, -88.3762626647949f);
  float fx = floorf(__builtin_fmaf(xc, 1.44269504088896341f, 0.5f));
  float tmp = 0.693359375f * fx;          // separate rounding (contract off)
  float z = -2.12194440e-4f * fx;
  float r = xc - tmp;
  r = r - z;
  z = r * r;
  float y = __builtin_fmaf(r, 1.9875691500e-4f, 1.3981999507e-3f);
  y = __builtin_fmaf(y, r, 8.3334519073e-3f);
  y = __builtin_fmaf(y, r, 4.1665795894e-2f);
  y = __builtin_fmaf(y, r, 1.6666665459e-1f);
  y = __builtin_fmaf(y, r, 5.0000001201e-1f);
  y = __builtin_fmaf(y, z, r);
  y = y + 1.0f;
  int n = (int)fx;
  float p2 = __int_as_float((n + 127) << 23);
  float res = y * p2;
  return fmaxf(res, x);                   // Eigen pexp: pmax(res, original x)
}

__device__ __forceinline__ float sigmoid_ref(float x) {
  float e = xla_expf(-x);                 // negate exact
  return 1.0f / (1.0f + e);               // IEEE fdiv (no fast-math)
}

// bern: partitionable threefry bits -> uniform [0,1) -> (u < p)
__device__ __forceinline__ float bern_sample(uint32_t key0, uint32_t key1,
                                             uint32_t idx, float p) {
  uint32_t b0, b1;
  tf2x32(key0, key1, 0u, idx, &b0, &b1);  // counter = (hi=0, lo=flat_idx)
  uint32_t bits = b0 ^ b1;                // 32-bit path XORs both words
  float u = __uint_as_float((bits >> 9) | 0x3f800000u) - 1.0f;
  return (u < p) ? 1.0f : 0.0f;
}

// ---------------- kernels ---------------------------------------------------
__global__ void k_transpose(const float* __restrict__ Whv,
                            float* __restrict__ WhvT) {
  int j = threadIdx.x;  // hidden
  int k = blockIdx.x;   // visible
  WhvT[k * NF + j] = Whv[j * NF + k];
}

// out[row][j] = sum_k u[row][k] * W[j][k], ascending k (exact products).
// W row j lives in registers; u-chunk (RTI rows x 64) broadcast from LDS.
__global__ __launch_bounds__(256, 2) void k_udot(const float* __restrict__ U,
                                                 const float* __restrict__ W,
                                                 float* __restrict__ out) {
  __shared__ __align__(16) float Ulds[NU * RTI];  // [k][i], 4 KiB
  const int j = threadIdx.x;
  const int i0 = blockIdx.x * RTI;
  const int si = j & 15;          // row within tile
  const int sg = j >> 4;          // 4-col group (16 groups cover 64 cols)
  {
    float4 u4 = *(const float4*)(U + (size_t)(i0 + si) * NU + sg * 4);
    Ulds[(sg * 4 + 0) * RTI + si] = u4.x;
    Ulds[(sg * 4 + 1) * RTI + si] = u4.y;
    Ulds[(sg * 4 + 2) * RTI + si] = u4.z;
    Ulds[(sg * 4 + 3) * RTI + si] = u4.w;
  }
  float wreg[NU];
  const float4* wr4 = (const float4*)(W + (size_t)j * NU);
#pragma unroll
  for (int r = 0; r < NU / 4; ++r) {
    float4 t = wr4[r];
    wreg[4 * r + 0] = t.x; wreg[4 * r + 1] = t.y;
    wreg[4 * r + 2] = t.z; wreg[4 * r + 3] = t.w;
  }
  __syncthreads();
  float acc[RTI];
#pragma unroll
  for (int i = 0; i < RTI; ++i) acc[i] = 0.0f;
#pragma unroll
  for (int kk = 0; kk < NU; ++kk) {
    const float w = wreg[kk];
    const float4 s0 = *(const float4*)(&Ulds[kk * RTI + 0]);
    const float4 s1 = *(const float4*)(&Ulds[kk * RTI + 4]);
    const float4 s2 = *(const float4*)(&Ulds[kk * RTI + 8]);
    const float4 s3 = *(const float4*)(&Ulds[kk * RTI + 12]);
    acc[0]  = __builtin_fmaf(s0.x, w, acc[0]);
    acc[1]  = __builtin_fmaf(s0.y, w, acc[1]);
    acc[2]  = __builtin_fmaf(s0.z, w, acc[2]);
    acc[3]  = __builtin_fmaf(s0.w, w, acc[3]);
    acc[4]  = __builtin_fmaf(s1.x, w, acc[4]);
    acc[5]  = __builtin_fmaf(s1.y, w, acc[5]);
    acc[6]  = __builtin_fmaf(s1.z, w, acc[6]);
    acc[7]  = __builtin_fmaf(s1.w, w, acc[7]);
    acc[8]  = __builtin_fmaf(s2.x, w, acc[8]);
    acc[9]  = __builtin_fmaf(s2.y, w, acc[9]);
    acc[10] = __builtin_fmaf(s2.z, w, acc[10]);
    acc[11] = __builtin_fmaf(s2.w, w, acc[11]);
    acc[12] = __builtin_fmaf(s3.x, w, acc[12]);
    acc[13] = __builtin_fmaf(s3.y, w, acc[13]);
    acc[14] = __builtin_fmaf(s3.z, w, acc[14]);
    acc[15] = __builtin_fmaf(s3.w, w, acc[15]);
  }
#pragma unroll
  for (int i = 0; i < RTI; ++i)
    out[(size_t)(i0 + i) * NF + j] = acc[i];   // row-major C (coalesced)
}

// v0 = bern(ks[0], sigmoid(uv + bv)); writes transposed state Vt[j][row]
__global__ __launch_bounds__(256) void k_init(const float* __restrict__ uv,
                                              const float* __restrict__ bv,
                                              float* __restrict__ Vt,
                                              uint32_t key0, uint32_t key1) {
  int j = threadIdx.x;
  int i0 = blockIdx.x * RTI;
  float b = bv[j];
  float vals[RTI];
#pragma unroll
  for (int i = 0; i < RTI; ++i) {
    int row = i0 + i;
    uint32_t idx = (uint32_t)(row * NF + j);
    float x = uv[idx] + b;                // (dot) + bias : single add
    float p = sigmoid_ref(x);
    vals[i] = bern_sample(key0, key1, idx, p);
  }
  float4* dst = (float4*)(Vt + (size_t)j * BATCH + i0);
#pragma unroll
  for (int q = 0; q < RTI / 4; ++q)
    dst[q] = make_float4(vals[4 * q], vals[4 * q + 1], vals[4 * q + 2], vals[4 * q + 3]);
}

// One Gibbs half-step: O = bern(key, sigmoid((St^T @ W) + C + bias))
// St: prev state transposed [256 k][8192 i]; W: [256 k][256 j] k-major;
// C: u-dot row-major [8192][256]; Ot: next state transposed; smp: int32 out.
// Block = 32 rows x 64 cols, thread tile 2x4. Full-k state slice
// [256k][32r] = 32 KiB staged once (1 barrier). k-loop = 2-stage pipeline
// with the emission order PINNED by sched_group_barrier:
// {4 VMEM_READ, 4 DS_READ, 32 VALU} per phase, last iteration peeled
// (branchless body = single scheduling region). Grid 1024 -> 4 blocks/CU;
// c0 = blockIdx>>8 so co-resident blocks share the same 64KB W slice.
__global__ __launch_bounds__(256, 4) void k_phase(const float* __restrict__ St,
                                                  const float* __restrict__ W,
                                                  const float* __restrict__ C,
                                                  const float* __restrict__ bias,
                                                  float* __restrict__ Ot,
                                                  int* __restrict__ smp,
                                                  uint32_t key0, uint32_t key1) {
  __shared__ __align__(16) float Slds[NF * RB];   // [k][row], 32 KiB
  const int t  = threadIdx.x;
  const int i0 = (blockIdx.x & 255) * RB;  // 256 row-blocks (consecutive ids)
  const int c0 = (blockIdx.x >> 8) * CBL;  // 4 col-blocks (CU-mates share W)
  const int rg = t >> 4;                   // 16 row-groups x 2 rows
  const int cg = t & 15;                   // 16 col-groups x 4 cols
  const int jc = c0 + cg * 4;              // this thread's first col

  // stage the whole-k state slice: 2048 float4, 8 per thread.
  // f = q*256+t -> k = f>>3 (8 float4 per 128B k-row), r4 = f&7: coalesced.
  {
    const float* stbase = St + i0;
    float4* sl4 = (float4*)Slds;
#pragma unroll
    for (int q = 0; q < 8; ++q) {
      const int f  = q * 256 + t;
      const int k  = f >> 3;
      const int r4 = f & 7;
      sl4[f] = *(const float4*)(stbase + (size_t)k * BATCH + r4 * 4);
    }
  }
  __syncthreads();

  float acc[8];                       // acc[ri*4+ci], ri in {0,1}
#pragma unroll
  for (int q = 0; q < 8; ++q) acc[q] = 0.0f;

  const float* wp = W + jc;           // this thread's 4 cols, stride NF per k
  const float* sl = Slds + rg * 2;    // this thread's 2 rows in the slice

  // ---- 2-stage software pipeline, groups of 4 k, sched_group_barrier-pinned
  float4 wA[4], wB[4];
  float2 sA[4], sB[4];
#define LDW(dst, kb)                                                      \
  _Pragma("unroll") for (int q = 0; q < 4; ++q)                           \
    dst[q] = *(const float4*)(wp + (size_t)((kb) + q) * NF);
#define LDSR(dst, kb)                                                     \
  _Pragma("unroll") for (int q = 0; q < 4; ++q)                           \
    dst[q] = *(const float2*)(sl + ((kb) + q) * RB);
#define FMA4(wb, sb)                                                      \
  _Pragma("unroll") for (int q = 0; q < 4; ++q) {                         \
    acc[0] = __builtin_fmaf(sb[q].x, wb[q].x, acc[0]);                    \
    acc[1] = __builtin_fmaf(sb[q].x, wb[q].y, acc[1]);                    \
    acc[2] = __builtin_fmaf(sb[q].x, wb[q].z, acc[2]);                    \
    acc[3] = __builtin_fmaf(sb[q].x, wb[q].w, acc[3]);                    \
    acc[4] = __builtin_fmaf(sb[q].y, wb[q].x, acc[4]);                    \
    acc[5] = __builtin_fmaf(sb[q].y, wb[q].y, acc[5]);                    \
    acc[6] = __builtin_fmaf(sb[q].y, wb[q].z, acc[6]);                    \
    acc[7] = __builtin_fmaf(sb[q].y, wb[q].w, acc[7]);                    \
  }
#define SGB_LOADS()                                                       \
  __builtin_amdgcn_sched_group_barrier(0x20, 4, 0);  /* 4 VMEM_READ */    \
  __builtin_amdgcn_sched_group_barrier(0x100, 4, 0); /* 4 DS_READ  */
#define SGB_FMA()                                                         \
  __builtin_amdgcn_sched_group_barrier(0x2, 32, 0);  /* 32 VALU    */

  LDW(wA, 0); LDSR(sA, 0);
  // branchless steady state: groups (kb, kb+4); loads run 1-2 groups ahead
  for (int kb = 0; kb < NF - 8; kb += 8) {
    LDW(wB, kb + 4); LDSR(sB, kb + 4);
    SGB_LOADS();
    FMA4(wA, sA);                         // compute group kb (k ascending)
    SGB_FMA();
    LDW(wA, kb + 8); LDSR(sA, kb + 8);
    SGB_LOADS();
    FMA4(wB, sB);                         // compute group kb+4
    SGB_FMA();
  }
  // peeled tail: wA holds group NF-8; load and compute final group NF-4
  LDW(wB, NF - 4); LDSR(sB, NF - 4);
  FMA4(wA, sA);
  FMA4(wB, sB);
#undef LDW
#undef LDSR
#undef FMA4
#undef SGB_LOADS
#undef SGB_FMA

  // epilogue: x = (dot + udot) + bias ; p = sigmoid ; bern ; store
  const float4 b4 = *(const float4*)(bias + jc);
  float vals[8];
#pragma unroll
  for (int ri = 0; ri < 2; ++ri) {
    const int row = i0 + rg * 2 + ri;
    const float4 c4 = *(const float4*)(C + (size_t)row * NF + jc);
    const uint32_t idx0 = (uint32_t)(row * NF + jc);
    vals[ri * 4 + 0] = bern_sample(key0, key1, idx0 + 0,
        sigmoid_ref((acc[ri * 4 + 0] + c4.x) + b4.x));
    vals[ri * 4 + 1] = bern_sample(key0, key1, idx0 + 1,
        sigmoid_ref((acc[ri * 4 + 1] + c4.y) + b4.y));
    vals[ri * 4 + 2] = bern_sample(key0, key1, idx0 + 2,
        sigmoid_ref((acc[ri * 4 + 2] + c4.z) + b4.z));
    vals[ri * 4 + 3] = bern_sample(key0, key1, idx0 + 3,
        sigmoid_ref((acc[ri * 4 + 3] + c4.w) + b4.w));
  }

  // next-state store (transposed): per col, the thread's 2 contiguous rows
#pragma unroll
  for (int ci = 0; ci < 4; ++ci) {
    *(float2*)(Ot + (size_t)(jc + ci) * BATCH + i0 + rg * 2) =
        make_float2(vals[0 + ci], vals[4 + ci]);
  }
  if (smp) {                          // row-major int32 sample output
#pragma unroll
    for (int ri = 0; ri < 2; ++ri) {
      const int row = i0 + rg * 2 + ri;
      int4 o;
      o.x = (vals[ri * 4 + 0] != 0.0f) ? 1 : 0;
      o.y = (vals[ri * 4 + 1] != 0.0f) ? 1 : 0;
      o.z = (vals[ri * 4 + 2] != 0.0f) ? 1 : 0;
      o.w = (vals[ri * 4 + 3] != 0.0f) ? 1 : 0;
      *(int4*)(smp + (size_t)row * NF + jc) = o;
    }
  }
}

// ---------------- launch ----------------------------------------------------
extern "C" void kernel_launch(void* const* d_in, const int* in_sizes, int n_in,
                              void* d_out, int out_size, void* d_ws, size_t ws_size,
                              hipStream_t stream) {
  const float* u_state = (const float*)d_in[0];  // [8192][64] 0/1 floats
  const float* Wvu     = (const float*)d_in[1];  // [256][64]
  const float* Whu     = (const float*)d_in[2];  // [256][64]
  const float* Whv     = (const float*)d_in[3];  // [256][256]
  const float* bv      = (const float*)d_in[4];  // [256]
  const float* bh      = (const float*)d_in[5];  // [256]
  int* out = (int*)d_out;                        // [8][8192][256] as int32 0/1

  // workspace layout (floats); total 8,454,144 f32 = 33.8 MB
  float* ws   = (float*)d_ws;
  float* WhvT = ws;                        // 65536
  float* uh   = WhvT + NF * NF;            // row-major [8192][256]
  float* uv   = uh + (size_t)BATCH * NF;
  float* Vt   = uv + (size_t)BATCH * NF;   // state, transposed [256][8192]
  float* Ht   = Vt + (size_t)BATCH * NF;

  // ---- host-side key schedule (pure CPU, deterministic) ----
  uint32_t s0[THERM + NSAMP + 1], s1[THERM + NSAMP + 1];
  for (uint32_t i = 0; i < THERM + NSAMP + 1; ++i)
    tf2x32(0u, 1u, 0u, i, &s0[i], &s1[i]);

  k_transpose<<<NF, NF, 0, stream>>>(Whv, WhvT);
  k_udot<<<BATCH / RTI, NF, 0, stream>>>(u_state, Whu, uh);   // u @ Whu.T
  k_udot<<<BATCH / RTI, NF, 0, stream>>>(u_state, Wvu, uv);   // u @ Wvu.T
  k_init<<<BATCH / RTI, NF, 0, stream>>>(uv, bv, Vt, s0[0], s1[0]);

  const int phase_blocks = (BATCH / RB) * (NF / CBL);   // 256 * 4 = 1024
  for (int t = 0; t < THERM + NSAMP; ++t) {
    uint32_t kh0, kh1, kv0, kv1;
    tf2x32(s0[1 + t], s1[1 + t], 0u, 0u, &kh0, &kh1);
    tf2x32(s0[1 + t], s1[1 + t], 0u, 1u, &kv0, &kv1);
    int* smp = (t >= THERM) ? out + (size_t)(t - THERM) * BATCH * NF : (int*)nullptr;
    // h = bern(k1, sigmoid(v @ Whv.T + uh + bh))
    k_phase<<<phase_blocks, NF, 0, stream>>>(Vt, WhvT, uh, bh, Ht, (int*)nullptr, kh0, kh1);
    // v = bern(k2, sigmoid(h @ Whv + uv + bv)) ; emit sample when t>=THERM
    k_phase<<<phase_blocks, NF, 0, stream>>>(Ht, Whv, uv, bv, Vt, smp, kv0, kv1);
  }
  (void)in_sizes; (void)n_in; (void)out_size; (void)ws_size;
}